// Round 8
// baseline (697.412 us; speedup 1.0000x reference)
//
#include <hip/hip_runtime.h>
#include <hip/hip_bf16.h>

#define NB_MAX 8192
#define NTHR 256

// scalars layout: [0]=P  [8]=g0 [9]=g1 [10]=g2 [11]=g1*g2 [12]=nb
//                 [13]=arrival counter  [14]=flag1 (cumc ready)  [15]=flag2 (blockoff ready)

// K1: count -> (full barrier via arrival counter, block 0 scans buckets, flag1) -> scatter/runlen/Oarr
__global__ __launch_bounds__(NTHR) void k_fused(
    const float* __restrict__ coord,
    const float* __restrict__ cell,
    float* __restrict__ out_frac,
    int* __restrict__ pv,
    int* __restrict__ counts,
    int* __restrict__ fill,
    int* __restrict__ scalars,
    int* __restrict__ cumc,
    int* __restrict__ pairoff,
    int* __restrict__ sorted,
    int* __restrict__ Oarr,
    int* __restrict__ blockpart,
    int n) {
  __shared__ int shA[4], shB[4];
  int t = threadIdx.x;
  int lane = t & 63, wid = t >> 6;
  int a = blockIdx.x * NTHR + t;
  bool active = a < n;

  // ---- Phase 1: frac out, bucket id + packed vec, histogram ----
  float d0 = cell[0], d1 = cell[4], d2 = cell[8];
  const float bl = (float)(5.2 + 1e-05);
  int g0 = (int)floorf(d0 / bl) + 1;
  int g1 = (int)floorf(d1 / bl) + 1;
  int g2 = (int)floorf(d2 / bl) + 1;
  int g12 = g1 * g2;
  if (a == 0) {
    scalars[8] = g0; scalars[9] = g1; scalars[10] = g2;
    scalars[11] = g12; scalars[12] = g0 * g12;
  }
  int flat_r = 0, pv_r = 0;
  if (active) {
    float x = coord[3 * a + 0], y = coord[3 * a + 1], z = coord[3 * a + 2];
    float fx = x / d0, fy = y / d1, fz = z / d2;
    out_frac[3 * a + 0] = fx;
    out_frac[3 * a + 1] = fy;
    out_frac[3 * a + 2] = fz;
    int v0 = (int)rintf(fx * (float)(g0 - 1));
    int v1 = (int)rintf(fy * (float)(g1 - 1));
    int v2 = (int)rintf(fz * (float)(g2 - 1));
    flat_r = v0 * g12 + v1 * g1 + v2;
    pv_r = (v0 << 20) | (v1 << 10) | v2;
    pv[a] = pv_r;
    atomicAdd(&counts[flat_r], 1);
  }

  // ---- Arrival barrier: all blocks arrive; block 0 waits for everyone ----
  __syncthreads();
  if (t == 0) {
    __threadfence();
    __hip_atomic_fetch_add(&scalars[13], 1, __ATOMIC_ACQ_REL, __HIP_MEMORY_SCOPE_AGENT);
    if (blockIdx.x == 0) {
      while (__hip_atomic_load(&scalars[13], __ATOMIC_ACQUIRE, __HIP_MEMORY_SCOPE_AGENT)
             < (int)gridDim.x) {
        __builtin_amdgcn_s_sleep(2);
      }
      __threadfence();
    }
  }
  __syncthreads();

  // ---- Phase 2: block 0 scans buckets -> cumc, pairoff, P; release flag1 ----
  if (blockIdx.x == 0) {
    int nb = scalars[12];
    const int IT = NB_MAX / NTHR;  // 32
    int base2 = t * IT;
    int lc = 0, lp = 0;
    for (int i = 0; i < IT; ++i) {
      int idx = base2 + i;
      int c = (idx < nb) ? counts[idx] : 0;
      lc += c;
      lp += c * (c - 1) / 2;
    }
    int ic = lc, ip = lp;
    for (int off = 1; off < 64; off <<= 1) {
      int yc = __shfl_up(ic, off);
      int yp = __shfl_up(ip, off);
      if (lane >= off) { ic += yc; ip += yp; }
    }
    if (lane == 63) { shA[wid] = ic; shB[wid] = ip; }
    __syncthreads();
    if (wid == 0 && lane < 4) {
      int vc2 = shA[lane], vp2 = shB[lane];
      int sc2 = vc2, sp2 = vp2;
      for (int off = 1; off < 4; off <<= 1) {
        int yc = __shfl_up(sc2, off);
        int yp = __shfl_up(sp2, off);
        if (lane >= off) { sc2 += yc; sp2 += yp; }
      }
      shA[lane] = sc2 - vc2;
      shB[lane] = sp2 - vp2;
    }
    __syncthreads();
    int ec = shA[wid] + (ic - lc);
    int ep = shB[wid] + (ip - lp);
    for (int i = 0; i < IT; ++i) {
      int idx = base2 + i;
      int c = (idx < nb) ? counts[idx] : 0;
      if (idx < nb) { cumc[idx] = ec; pairoff[idx] = ep; }
      ec += c;
      ep += c * (c - 1) / 2;
    }
    if (t == NTHR - 1) scalars[0] = ep;  // total P
    __syncthreads();
    if (t == 0) {
      __threadfence();
      __hip_atomic_store(&scalars[14], 1, __ATOMIC_RELEASE, __HIP_MEMORY_SCOPE_AGENT);
    }
    __syncthreads();
  } else {
    if (t == 0) {
      while (__hip_atomic_load(&scalars[14], __ATOMIC_ACQUIRE, __HIP_MEMORY_SCOPE_AGENT) == 0) {
        __builtin_amdgcn_s_sleep(2);
      }
      __threadfence();
    }
    __syncthreads();
  }

  // ---- Phase 3: scatter + run length S + block-local offsets ----
  int S = 0;
  if (active) {
    int pos = cumc[flat_r] + atomicAdd(&fill[flat_r], 1);
    sorted[pos] = a;
    int v0 = pv_r >> 20, v1 = (pv_r >> 10) & 1023, v2 = pv_r & 1023;
#pragma unroll
    for (int m = 0; m < 7; ++m) {
      int dx = ((m >> 2) & 1) ? 0 : -1;
      int dy = ((m >> 1) & 1) ? 0 : -1;
      int dz = (m & 1) ? 0 : -1;
      int nx = v0 + dx; if (nx < 0) nx += g0;
      int ny = v1 + dy; if (ny < 0) ny += g1;
      int nz = v2 + dz; if (nz < 0) nz += g2;
      S += counts[nx * g12 + ny * g1 + nz];
    }
  }
  int iv = S;
  for (int off = 1; off < 64; off <<= 1) {
    int y = __shfl_up(iv, off);
    if (lane >= off) iv += y;
  }
  if (lane == 63) shA[wid] = iv;
  __syncthreads();
  if (wid == 0 && lane < 4) {
    int v2 = shA[lane], s2 = v2;
    for (int off = 1; off < 4; off <<= 1) {
      int y = __shfl_up(s2, off);
      if (lane >= off) s2 += y;
    }
    shA[lane] = s2 - v2;
    if (lane == 3) blockpart[blockIdx.x] = s2;
  }
  __syncthreads();
  if (active) Oarr[a] = shA[wid] + (iv - S);
}

// K2: block 0: blockoff scan + flag2. Blocks 1..2048: sort/perm/pairs.
//     Blocks 2049..: emit (spin flag2 first).
__global__ __launch_bounds__(NTHR) void k_mega(
    const int* __restrict__ counts,
    const int* __restrict__ cumc,
    const int* __restrict__ pairoff,
    int* __restrict__ scalars,
    int* __restrict__ sorted,
    const int* __restrict__ pv,
    const int* __restrict__ Oarr,
    const int* __restrict__ blockpart,
    int* __restrict__ blockoff,
    float* __restrict__ out_im,
    float* __restrict__ out_at,
    float* __restrict__ out,
    int nblocks, int n) {
  int t = threadIdx.x;
  int lane = t & 63, wid = t >> 6;

  if (blockIdx.x == 0) {
    // exclusive scan of blockpart[0..nblocks) by wave 0 (lane-strided, 7/lane -> 448)
    if (wid == 0) {
      int cv[7];
      int ls = 0;
      for (int i = 0; i < 7; ++i) {
        int idx = lane * 7 + i;
        int v = (idx < nblocks) ? blockpart[idx] : 0;
        cv[i] = v;
        ls += v;
      }
      int il = ls;
      for (int off = 1; off < 64; off <<= 1) {
        int y = __shfl_up(il, off);
        if (lane >= off) il += y;
      }
      int e = il - ls;
      for (int i = 0; i < 7; ++i) {
        int idx = lane * 7 + i;
        if (idx < nblocks) blockoff[idx] = e;
        e += cv[i];
      }
    }
    __syncthreads();
    if (t == 0) {
      __threadfence();
      __hip_atomic_store(&scalars[15], 1, __ATOMIC_RELEASE, __HIP_MEMORY_SCOPE_AGENT);
    }
    return;
  }

  if (blockIdx.x <= 2048) {
    // per-bucket sort/perm/pairs (4 buckets per block, 1 per wave)
    int b = (blockIdx.x - 1) * 4 + wid;
    int nb = scalars[12];
    if (b >= nb) return;
    int c = counts[b];
    if (c == 0) return;
    int s = cumc[b];
    if (c == 1) {
      if (lane == 0) {
        int aa = sorted[s];
        out_im[s] = (float)aa;
        out_at[aa] = (float)s;
      }
      return;
    }
    if (c <= 64) {
      int val = (lane < c) ? sorted[s + lane] : 0x7fffffff;
      int rank = 0;
      for (int j = 0; j < c; ++j) {
        int other = __shfl(val, j);
        rank += (other < val) ? 1 : 0;
      }
      if (lane < c) {
        sorted[s + rank] = val;
        out_im[s + rank] = (float)val;
        out_at[val] = (float)(s + rank);
      }
    } else if (lane == 0) {
      for (int i = 1; i < c; ++i) {
        int key = sorted[s + i];
        int j = i - 1;
        while (j >= 0 && sorted[s + j] > key) {
          sorted[s + j + 1] = sorted[s + j];
          --j;
        }
        sorted[s + j + 1] = key;
      }
      for (int i = 0; i < c; ++i) {
        int aa = sorted[s + i];
        out_im[s + i] = (float)aa;
        out_at[aa] = (float)(s + i);
      }
    }
    int off = pairoff[b];
    int P = scalars[0];
    int np = c * (c - 1) / 2;
    for (int k = lane; k < np; k += 64) {
      int l = (int)((1.0f + sqrtf(1.0f + 8.0f * (float)k)) * 0.5f);
      while (l * (l - 1) / 2 > k) --l;
      while ((l + 1) * l / 2 <= k) ++l;
      int u = k - l * (l - 1) / 2;
      out[off + k] = (float)(s + u);
      out[P + off + k] = (float)(s + l);
    }
    return;
  }

  // ---- emit: wait for blockoff, then 16-lane-group coalesced emit ----
  if (t == 0) {
    while (__hip_atomic_load(&scalars[15], __ATOMIC_ACQUIRE, __HIP_MEMORY_SCOPE_AGENT) == 0) {
      __builtin_amdgcn_s_sleep(4);
    }
    __threadfence();
  }
  __syncthreads();
  int e = blockIdx.x - 2049;
  int a = e * 16 + (t >> 4);
  int l16 = t & 15;
  if (a >= n) return;
  int g0 = scalars[8], g1 = scalars[9], g2 = scalars[10], g12 = scalars[11];
  int p = pv[a];
  int v0 = p >> 20, v1 = (p >> 10) & 1023, v2 = p & 1023;
  int segs[8];
  int cums[7];
  segs[0] = 0;
#pragma unroll
  for (int m = 0; m < 7; ++m) {
    int dx = ((m >> 2) & 1) ? 0 : -1;
    int dy = ((m >> 1) & 1) ? 0 : -1;
    int dz = (m & 1) ? 0 : -1;
    int nx = v0 + dx; if (nx < 0) nx += g0;
    int ny = v1 + dy; if (ny < 0) ny += g1;
    int nz = v2 + dz; if (nz < 0) nz += g2;
    int nb_ = nx * g12 + ny * g1 + nz;
    cums[m] = cumc[nb_];
    segs[m + 1] = segs[m] + counts[nb_];
  }
  int S = segs[7];
  long base = 2L * (long)scalars[0] + (long)blockoff[a >> 8] + (long)Oarr[a];
  for (int q = l16; q < S; q += 16) {
    int v = cums[0] + q;
#pragma unroll
    for (int m = 1; m < 7; ++m) {
      if (q >= segs[m]) v = cums[m] + (q - segs[m]);
    }
    out[base + q] = (float)v;
  }
}

extern "C" void kernel_launch(void* const* d_in, const int* in_sizes, int n_in,
                              void* d_out, int out_size, void* d_ws, size_t ws_size,
                              hipStream_t stream) {
  const float* coord = (const float*)d_in[0];
  const float* cell = (const float*)d_in[1];
  float* out = (float*)d_out;
  int n = in_sizes[0] / 3;

  int* W = (int*)d_ws;
  int* counts = W;                         // NB_MAX
  int* fill = W + NB_MAX;                  // NB_MAX
  int* scalars = W + 2 * NB_MAX;           // 16 (zeroed: P, done, flags)
  int* cumc = W + 2 * NB_MAX + 16;         // NB_MAX
  int* pairoff = cumc + NB_MAX;            // NB_MAX
  int* pv = pairoff + NB_MAX;              // n
  int* sorted = pv + n;                    // n
  int* Oarr = sorted + n;                  // n
  int* blockpart = Oarr + n;               // 1024
  int* blockoff = blockpart + 1024;        // 1024

  // output chunk bases known on host: out = [2P | L | 3n | n | n]
  float* out_frac = out + (out_size - 5 * n);
  float* out_im = out + (out_size - 2 * n);
  float* out_at = out + (out_size - n);

  int nblocks = (n + NTHR - 1) / NTHR;     // 391
  int eblocks = (n + 15) / 16;             // 16 lanes per atom, 16 atoms per block
  int megagrid = 1 + 2048 + eblocks;

  hipMemsetAsync(d_ws, 0, (size_t)(2 * NB_MAX + 16) * sizeof(int), stream);

  k_fused<<<nblocks, NTHR, 0, stream>>>(coord, cell, out_frac, pv, counts, fill,
                                        scalars, cumc, pairoff, sorted, Oarr,
                                        blockpart, n);
  k_mega<<<megagrid, NTHR, 0, stream>>>(counts, cumc, pairoff, scalars, sorted,
                                        pv, Oarr, blockpart, blockoff,
                                        out_im, out_at, out, nblocks, n);
}

// Round 9
// 198.024 us; speedup vs baseline: 3.5219x; 3.5219x over previous
//
#include <hip/hip_runtime.h>
#include <hip/hip_bf16.h>

#define NB_MAX 8192
#define NTHR 256

// scalars: [0]=P  [8]=g0 [9]=g1 [10]=g2 [11]=g1*g2 [12]=nb  [13]=doneA [14]=doneB

// K_A: per-atom frac/pv/histogram; LAST-FINISHING block scans buckets -> cumc/pairoff/P.
// (No spinning: the block whose done-counter increment returns gridDim-1 does the scan.)
__global__ __launch_bounds__(NTHR) void k_a(
    const float* __restrict__ coord,
    const float* __restrict__ cell,
    float* __restrict__ out_frac,
    int* __restrict__ pv,
    int* __restrict__ counts,
    int* __restrict__ scalars,
    int* __restrict__ cumc,
    int* __restrict__ pairoff,
    int n) {
  __shared__ int shA[4], shB[4];
  __shared__ int isLast;
  int t = threadIdx.x;
  int lane = t & 63, wid = t >> 6;
  int a = blockIdx.x * NTHR + t;

  float d0 = cell[0], d1 = cell[4], d2 = cell[8];
  const float bl = (float)(5.2 + 1e-05);
  int g0 = (int)floorf(d0 / bl) + 1;
  int g1 = (int)floorf(d1 / bl) + 1;
  int g2 = (int)floorf(d2 / bl) + 1;
  int g12 = g1 * g2;
  if (a == 0) {
    scalars[8] = g0; scalars[9] = g1; scalars[10] = g2;
    scalars[11] = g12; scalars[12] = g0 * g12;
  }
  if (a < n) {
    float x = coord[3 * a + 0], y = coord[3 * a + 1], z = coord[3 * a + 2];
    float fx = x / d0, fy = y / d1, fz = z / d2;
    out_frac[3 * a + 0] = fx;
    out_frac[3 * a + 1] = fy;
    out_frac[3 * a + 2] = fz;
    int v0 = (int)rintf(fx * (float)(g0 - 1));
    int v1 = (int)rintf(fy * (float)(g1 - 1));
    int v2 = (int)rintf(fz * (float)(g2 - 1));
    pv[a] = (v0 << 20) | (v1 << 10) | v2;
    atomicAdd(&counts[v0 * g12 + v1 * g1 + v2], 1);
  }

  // last-finishing-block detection (no waiting)
  __threadfence();
  __syncthreads();
  if (t == 0) {
    int old = __hip_atomic_fetch_add(&scalars[13], 1, __ATOMIC_ACQ_REL,
                                     __HIP_MEMORY_SCOPE_AGENT);
    isLast = (old == (int)gridDim.x - 1) ? 1 : 0;
  }
  __syncthreads();
  if (!isLast) return;
  __threadfence();  // acquire all counts

  // bucket scan: 256 threads x 32 buckets
  int nb = g0 * g12;
  const int IT = NB_MAX / NTHR;
  int base2 = t * IT;
  int lc = 0, lp = 0;
  for (int i = 0; i < IT; ++i) {
    int idx = base2 + i;
    int c = (idx < nb) ? counts[idx] : 0;
    lc += c;
    lp += c * (c - 1) / 2;
  }
  int ic = lc, ip = lp;
  for (int off = 1; off < 64; off <<= 1) {
    int yc = __shfl_up(ic, off);
    int yp = __shfl_up(ip, off);
    if (lane >= off) { ic += yc; ip += yp; }
  }
  if (lane == 63) { shA[wid] = ic; shB[wid] = ip; }
  __syncthreads();
  if (wid == 0 && lane < 4) {
    int vc2 = shA[lane], vp2 = shB[lane];
    int sc2 = vc2, sp2 = vp2;
    for (int off = 1; off < 4; off <<= 1) {
      int yc = __shfl_up(sc2, off);
      int yp = __shfl_up(sp2, off);
      if (lane >= off) { sc2 += yc; sp2 += yp; }
    }
    shA[lane] = sc2 - vc2;
    shB[lane] = sp2 - vp2;
  }
  __syncthreads();
  int ec = shA[wid] + (ic - lc);
  int ep = shB[wid] + (ip - lp);
  for (int i = 0; i < IT; ++i) {
    int idx = base2 + i;
    int c = (idx < nb) ? counts[idx] : 0;
    if (idx < nb) { cumc[idx] = ec; pairoff[idx] = ep; }
    ec += c;
    ep += c * (c - 1) / 2;
  }
  if (t == NTHR - 1) scalars[0] = ep;  // total P
}

// K_B: scatter + run length + block-local offsets; LAST block scans blockpart -> blockoff.
__global__ __launch_bounds__(NTHR) void k_b(
    const int* __restrict__ pv,
    const int* __restrict__ cumc,
    const int* __restrict__ counts,
    int* __restrict__ scalars,
    int* __restrict__ fill,
    int* __restrict__ sorted,
    int* __restrict__ Oarr,
    int* __restrict__ blockpart,
    int* __restrict__ blockoff,
    int n) {
  __shared__ int shA[4];
  __shared__ int isLast;
  int t = threadIdx.x;
  int lane = t & 63, wid = t >> 6;
  int a = blockIdx.x * NTHR + t;
  int g0 = scalars[8], g1 = scalars[9], g2 = scalars[10], g12 = scalars[11];
  int S = 0;
  if (a < n) {
    int p = pv[a];
    int v0 = p >> 20, v1 = (p >> 10) & 1023, v2 = p & 1023;
    int b = v0 * g12 + v1 * g1 + v2;
    int pos = cumc[b] + atomicAdd(&fill[b], 1);
    sorted[pos] = a;
#pragma unroll
    for (int m = 0; m < 7; ++m) {
      int dx = ((m >> 2) & 1) ? 0 : -1;
      int dy = ((m >> 1) & 1) ? 0 : -1;
      int dz = (m & 1) ? 0 : -1;
      int nx = v0 + dx; if (nx < 0) nx += g0;
      int ny = v1 + dy; if (ny < 0) ny += g1;
      int nz = v2 + dz; if (nz < 0) nz += g2;
      S += counts[nx * g12 + ny * g1 + nz];
    }
  }
  int iv = S;
  for (int off = 1; off < 64; off <<= 1) {
    int y = __shfl_up(iv, off);
    if (lane >= off) iv += y;
  }
  if (lane == 63) shA[wid] = iv;
  __syncthreads();
  if (wid == 0 && lane < 4) {
    int v2 = shA[lane], s2 = v2;
    for (int off = 1; off < 4; off <<= 1) {
      int y = __shfl_up(s2, off);
      if (lane >= off) s2 += y;
    }
    shA[lane] = s2 - v2;
    if (lane == 3) blockpart[blockIdx.x] = s2;
  }
  __syncthreads();
  if (a < n) Oarr[a] = shA[wid] + (iv - S);

  // last-finishing block scans blockpart -> blockoff (exclusive)
  __threadfence();
  __syncthreads();
  if (t == 0) {
    int old = __hip_atomic_fetch_add(&scalars[14], 1, __ATOMIC_ACQ_REL,
                                     __HIP_MEMORY_SCOPE_AGENT);
    isLast = (old == (int)gridDim.x - 1) ? 1 : 0;
  }
  __syncthreads();
  if (!isLast) return;
  __threadfence();
  int nblocks = gridDim.x;
  const int IT = 2;  // 256 threads x 2 = 512 >= nblocks
  int base2 = t * IT;
  int cv[IT];
  int ls = 0;
  for (int i = 0; i < IT; ++i) {
    int idx = base2 + i;
    int v = (idx < nblocks) ? blockpart[idx] : 0;
    cv[i] = v;
    ls += v;
  }
  int il = ls;
  for (int off = 1; off < 64; off <<= 1) {
    int y = __shfl_up(il, off);
    if (lane >= off) il += y;
  }
  if (lane == 63) shA[wid] = il;
  __syncthreads();
  if (wid == 0 && lane < 4) {
    int v2 = shA[lane], s2 = v2;
    for (int off = 1; off < 4; off <<= 1) {
      int y = __shfl_up(s2, off);
      if (lane >= off) s2 += y;
    }
    shA[lane] = s2 - v2;
  }
  __syncthreads();
  int e = shA[wid] + (il - ls);
  for (int i = 0; i < IT; ++i) {
    int idx = base2 + i;
    if (idx < nblocks) blockoff[idx] = e;
    e += cv[i];
  }
}

// K_C: merged grid. Blocks [0,2048): per-bucket sort/perm/pairs. Blocks [2048,..): emit16.
__global__ __launch_bounds__(NTHR) void k_c(
    const int* __restrict__ counts,
    const int* __restrict__ cumc,
    const int* __restrict__ pairoff,
    const int* __restrict__ scalars,
    int* __restrict__ sorted,
    const int* __restrict__ pv,
    const int* __restrict__ Oarr,
    const int* __restrict__ blockoff,
    float* __restrict__ out_im,
    float* __restrict__ out_at,
    float* __restrict__ out,
    int n) {
  int t = threadIdx.x;
  int lane = t & 63, wid = t >> 6;

  if (blockIdx.x < 2048) {
    int b = blockIdx.x * 4 + wid;
    int nb = scalars[12];
    if (b >= nb) return;
    int c = counts[b];
    if (c == 0) return;
    int s = cumc[b];
    if (c == 1) {
      if (lane == 0) {
        int aa = sorted[s];
        out_im[s] = (float)aa;
        out_at[aa] = (float)s;
      }
      return;
    }
    if (c <= 64) {
      int val = (lane < c) ? sorted[s + lane] : 0x7fffffff;
      int rank = 0;
      for (int j = 0; j < c; ++j) {
        int other = __shfl(val, j);
        rank += (other < val) ? 1 : 0;
      }
      if (lane < c) {
        sorted[s + rank] = val;
        out_im[s + rank] = (float)val;
        out_at[val] = (float)(s + rank);
      }
    } else if (lane == 0) {
      for (int i = 1; i < c; ++i) {
        int key = sorted[s + i];
        int j = i - 1;
        while (j >= 0 && sorted[s + j] > key) {
          sorted[s + j + 1] = sorted[s + j];
          --j;
        }
        sorted[s + j + 1] = key;
      }
      for (int i = 0; i < c; ++i) {
        int aa = sorted[s + i];
        out_im[s + i] = (float)aa;
        out_at[aa] = (float)(s + i);
      }
    }
    int off = pairoff[b];
    int P = scalars[0];
    int np = c * (c - 1) / 2;
    for (int k = lane; k < np; k += 64) {
      int l = (int)((1.0f + sqrtf(1.0f + 8.0f * (float)k)) * 0.5f);
      while (l * (l - 1) / 2 > k) --l;
      while ((l + 1) * l / 2 <= k) ++l;
      int u = k - l * (l - 1) / 2;
      out[off + k] = (float)(s + u);
      out[P + off + k] = (float)(s + l);
    }
    return;
  }

  // emit: 16 lanes per atom, 16 atoms per block
  int a = (blockIdx.x - 2048) * 16 + (t >> 4);
  int l16 = t & 15;
  if (a >= n) return;
  int g0 = scalars[8], g1 = scalars[9], g2 = scalars[10], g12 = scalars[11];
  int p = pv[a];
  int v0 = p >> 20, v1 = (p >> 10) & 1023, v2 = p & 1023;
  int segs[8];
  int cums[7];
  segs[0] = 0;
#pragma unroll
  for (int m = 0; m < 7; ++m) {
    int dx = ((m >> 2) & 1) ? 0 : -1;
    int dy = ((m >> 1) & 1) ? 0 : -1;
    int dz = (m & 1) ? 0 : -1;
    int nx = v0 + dx; if (nx < 0) nx += g0;
    int ny = v1 + dy; if (ny < 0) ny += g1;
    int nz = v2 + dz; if (nz < 0) nz += g2;
    int nb_ = nx * g12 + ny * g1 + nz;
    cums[m] = cumc[nb_];
    segs[m + 1] = segs[m] + counts[nb_];
  }
  int S = segs[7];
  long base = 2L * (long)scalars[0] + (long)blockoff[a >> 8] + (long)Oarr[a];
  for (int q = l16; q < S; q += 16) {
    int v = cums[0] + q;
#pragma unroll
    for (int m = 1; m < 7; ++m) {
      if (q >= segs[m]) v = cums[m] + (q - segs[m]);
    }
    out[base + q] = (float)v;
  }
}

extern "C" void kernel_launch(void* const* d_in, const int* in_sizes, int n_in,
                              void* d_out, int out_size, void* d_ws, size_t ws_size,
                              hipStream_t stream) {
  const float* coord = (const float*)d_in[0];
  const float* cell = (const float*)d_in[1];
  float* out = (float*)d_out;
  int n = in_sizes[0] / 3;

  int* W = (int*)d_ws;
  int* counts = W;                         // NB_MAX
  int* fill = W + NB_MAX;                  // NB_MAX
  int* scalars = W + 2 * NB_MAX;           // 16 (zeroed)
  int* cumc = W + 2 * NB_MAX + 16;         // NB_MAX
  int* pairoff = cumc + NB_MAX;            // NB_MAX
  int* pv = pairoff + NB_MAX;              // n
  int* sorted = pv + n;                    // n
  int* Oarr = sorted + n;                  // n
  int* blockpart = Oarr + n;               // 1024
  int* blockoff = blockpart + 1024;        // 1024

  // output chunk bases known on host: out = [2P | L | 3n | n | n]
  float* out_frac = out + (out_size - 5 * n);
  float* out_im = out + (out_size - 2 * n);
  float* out_at = out + (out_size - n);

  int nblocks = (n + NTHR - 1) / NTHR;     // 391
  int eblocks = (n + 15) / 16;             // emit blocks (16 atoms each)

  hipMemsetAsync(d_ws, 0, (size_t)(2 * NB_MAX + 16) * sizeof(int), stream);

  k_a<<<nblocks, NTHR, 0, stream>>>(coord, cell, out_frac, pv, counts, scalars,
                                    cumc, pairoff, n);
  k_b<<<nblocks, NTHR, 0, stream>>>(pv, cumc, counts, scalars, fill, sorted,
                                    Oarr, blockpart, blockoff, n);
  k_c<<<2048 + eblocks, NTHR, 0, stream>>>(counts, cumc, pairoff, scalars, sorted,
                                           pv, Oarr, blockoff, out_im, out_at, out, n);
}

// Round 10
// 114.862 us; speedup vs baseline: 6.0717x; 1.7240x over previous
//
#include <hip/hip_runtime.h>
#include <hip/hip_bf16.h>

#define NB_MAX 8192
#define NTHR 256

// scalars: [0]=P  [8]=g0 [9]=g1 [10]=g2 [11]=g1*g2 [12]=nb  [13]=doneA [14]=doneB
// Cross-block sync rules learned on this chip (rounds 7-9):
//   grid.sync ~45us; spin-flags >100us; per-thread agent fences ~60us/kernel.
//   ONLY cheap pattern: relaxed agent atomics + last-finishing-block (no waiting).

// K1: per-atom frac/pv/histogram; LAST-FINISHING block scans buckets -> cumc/pairoff/P.
__global__ __launch_bounds__(NTHR) void k_count(
    const float* __restrict__ coord,
    const float* __restrict__ cell,
    float* __restrict__ out_frac,
    int* __restrict__ pv,
    int* __restrict__ counts,
    int* __restrict__ scalars,
    int* __restrict__ cumc,
    int* __restrict__ pairoff,
    int n) {
  __shared__ int shA[4], shB[4];
  __shared__ int isLast;
  int t = threadIdx.x;
  int lane = t & 63, wid = t >> 6;
  int a = blockIdx.x * NTHR + t;

  float d0 = cell[0], d1 = cell[4], d2 = cell[8];
  const float bl = (float)(5.2 + 1e-05);
  int g0 = (int)floorf(d0 / bl) + 1;
  int g1 = (int)floorf(d1 / bl) + 1;
  int g2 = (int)floorf(d2 / bl) + 1;
  int g12 = g1 * g2;
  if (a == 0) {
    scalars[8] = g0; scalars[9] = g1; scalars[10] = g2;
    scalars[11] = g12; scalars[12] = g0 * g12;
  }
  if (a < n) {
    float x = coord[3 * a + 0], y = coord[3 * a + 1], z = coord[3 * a + 2];
    float fx = x / d0, fy = y / d1, fz = z / d2;
    out_frac[3 * a + 0] = fx;
    out_frac[3 * a + 1] = fy;
    out_frac[3 * a + 2] = fz;
    int v0 = (int)rintf(fx * (float)(g0 - 1));
    int v1 = (int)rintf(fy * (float)(g1 - 1));
    int v2 = (int)rintf(fz * (float)(g2 - 1));
    pv[a] = (v0 << 20) | (v1 << 10) | v2;
    atomicAdd(&counts[v0 * g12 + v1 * g1 + v2], 1);  // device-scope, coherent point
  }

  // __syncthreads drains vmcnt -> this block's atomics are performed before t0's add.
  __syncthreads();
  if (t == 0) {
    int old = __hip_atomic_fetch_add(&scalars[13], 1, __ATOMIC_RELAXED,
                                     __HIP_MEMORY_SCOPE_AGENT);
    isLast = (old == (int)gridDim.x - 1) ? 1 : 0;
  }
  __syncthreads();
  if (!isLast) return;

  // bucket scan (256 thr x 32); counts via relaxed agent atomic loads (coherent reads)
  int nb = g0 * g12;
  const int IT = NB_MAX / NTHR;  // 32
  int base2 = t * IT;
  int cv[IT];
  int lc = 0, lp = 0;
#pragma unroll
  for (int i = 0; i < IT; ++i) {
    int idx = base2 + i;
    int c = (idx < nb)
        ? __hip_atomic_load(&counts[idx], __ATOMIC_RELAXED, __HIP_MEMORY_SCOPE_AGENT)
        : 0;
    cv[i] = c;
    lc += c;
    lp += c * (c - 1) / 2;
  }
  int ic = lc, ip = lp;
  for (int off = 1; off < 64; off <<= 1) {
    int yc = __shfl_up(ic, off);
    int yp = __shfl_up(ip, off);
    if (lane >= off) { ic += yc; ip += yp; }
  }
  if (lane == 63) { shA[wid] = ic; shB[wid] = ip; }
  __syncthreads();
  if (wid == 0 && lane < 4) {
    int vc2 = shA[lane], vp2 = shB[lane];
    int sc2 = vc2, sp2 = vp2;
    for (int off = 1; off < 4; off <<= 1) {
      int yc = __shfl_up(sc2, off);
      int yp = __shfl_up(sp2, off);
      if (lane >= off) { sc2 += yc; sp2 += yp; }
    }
    shA[lane] = sc2 - vc2;
    shB[lane] = sp2 - vp2;
  }
  __syncthreads();
  int ec = shA[wid] + (ic - lc);
  int ep = shB[wid] + (ip - lp);
#pragma unroll
  for (int i = 0; i < IT; ++i) {
    int idx = base2 + i;
    if (idx < nb) { cumc[idx] = ec; pairoff[idx] = ep; }
    ec += cv[i];
    ep += cv[i] * (cv[i] - 1) / 2;
  }
  if (t == NTHR - 1) scalars[0] = ep;  // total P (plain store; next kernel sees it)
}

// K2: scatter + run length + block-local offsets; LAST-FINISHING block scans
//     blockpart -> blockoff.
__global__ __launch_bounds__(NTHR) void k_scatter(
    const int* __restrict__ pv,
    const int* __restrict__ cumc,
    const int* __restrict__ counts,
    int* __restrict__ scalars,
    int* __restrict__ fill,
    int* __restrict__ sorted,
    int* __restrict__ Oarr,
    int* __restrict__ blockpart,
    int* __restrict__ blockoff,
    int n) {
  __shared__ int shA[4];
  __shared__ int isLast;
  int t = threadIdx.x;
  int lane = t & 63, wid = t >> 6;
  int a = blockIdx.x * NTHR + t;
  int g0 = scalars[8], g1 = scalars[9], g2 = scalars[10], g12 = scalars[11];
  int S = 0;
  if (a < n) {
    int p = pv[a];
    int v0 = p >> 20, v1 = (p >> 10) & 1023, v2 = p & 1023;
    int b = v0 * g12 + v1 * g1 + v2;
    int pos = cumc[b] + atomicAdd(&fill[b], 1);
    sorted[pos] = a;
#pragma unroll
    for (int m = 0; m < 7; ++m) {
      int dx = ((m >> 2) & 1) ? 0 : -1;
      int dy = ((m >> 1) & 1) ? 0 : -1;
      int dz = (m & 1) ? 0 : -1;
      int nx = v0 + dx; if (nx < 0) nx += g0;
      int ny = v1 + dy; if (ny < 0) ny += g1;
      int nz = v2 + dz; if (nz < 0) nz += g2;
      S += counts[nx * g12 + ny * g1 + nz];
    }
  }
  int iv = S;
  for (int off = 1; off < 64; off <<= 1) {
    int y = __shfl_up(iv, off);
    if (lane >= off) iv += y;
  }
  if (lane == 63) shA[wid] = iv;
  __syncthreads();
  if (wid == 0 && lane < 4) {
    int v2 = shA[lane], s2 = v2;
    for (int off = 1; off < 4; off <<= 1) {
      int y = __shfl_up(s2, off);
      if (lane >= off) s2 += y;
    }
    shA[lane] = s2 - v2;
    if (lane == 3) {
      // agent-scope relaxed atomic store: coherently visible to last block's loads
      __hip_atomic_store(&blockpart[blockIdx.x], s2, __ATOMIC_RELAXED,
                         __HIP_MEMORY_SCOPE_AGENT);
    }
  }
  __syncthreads();
  if (a < n) Oarr[a] = shA[wid] + (iv - S);

  // last-finishing-block detection (syncthreads drained vmcnt incl. the atomic store)
  __syncthreads();
  if (t == 0) {
    int old = __hip_atomic_fetch_add(&scalars[14], 1, __ATOMIC_RELAXED,
                                     __HIP_MEMORY_SCOPE_AGENT);
    isLast = (old == (int)gridDim.x - 1) ? 1 : 0;
  }
  __syncthreads();
  if (!isLast) return;

  int nblocks = gridDim.x;
  const int IT = 2;  // 256 x 2 = 512 >= nblocks
  int base2 = t * IT;
  int cv[IT];
  int ls = 0;
#pragma unroll
  for (int i = 0; i < IT; ++i) {
    int idx = base2 + i;
    int v = (idx < nblocks)
        ? __hip_atomic_load(&blockpart[idx], __ATOMIC_RELAXED, __HIP_MEMORY_SCOPE_AGENT)
        : 0;
    cv[i] = v;
    ls += v;
  }
  int il = ls;
  for (int off = 1; off < 64; off <<= 1) {
    int y = __shfl_up(il, off);
    if (lane >= off) il += y;
  }
  if (lane == 63) shA[wid] = il;
  __syncthreads();
  if (wid == 0 && lane < 4) {
    int v2 = shA[lane], s2 = v2;
    for (int off = 1; off < 4; off <<= 1) {
      int y = __shfl_up(s2, off);
      if (lane >= off) s2 += y;
    }
    shA[lane] = s2 - v2;
  }
  __syncthreads();
  int e = shA[wid] + (il - ls);
#pragma unroll
  for (int i = 0; i < IT; ++i) {
    int idx = base2 + i;
    if (idx < nblocks) blockoff[idx] = e;  // plain store; read next kernel
    e += cv[i];
  }
}

// K3: merged grid. Blocks [0,2048): per-bucket sort/perm/pairs. Blocks [2048,..): emit16.
__global__ __launch_bounds__(NTHR) void k_sortemit(
    const int* __restrict__ counts,
    const int* __restrict__ cumc,
    const int* __restrict__ pairoff,
    const int* __restrict__ scalars,
    int* __restrict__ sorted,
    const int* __restrict__ pv,
    const int* __restrict__ Oarr,
    const int* __restrict__ blockoff,
    float* __restrict__ out_im,
    float* __restrict__ out_at,
    float* __restrict__ out,
    int n) {
  int t = threadIdx.x;
  int lane = t & 63, wid = t >> 6;

  if (blockIdx.x < 2048) {
    int b = blockIdx.x * 4 + wid;
    int nb = scalars[12];
    if (b >= nb) return;
    int c = counts[b];
    if (c == 0) return;
    int s = cumc[b];
    if (c == 1) {
      if (lane == 0) {
        int aa = sorted[s];
        out_im[s] = (float)aa;
        out_at[aa] = (float)s;
      }
      return;
    }
    if (c <= 64) {
      int val = (lane < c) ? sorted[s + lane] : 0x7fffffff;
      int rank = 0;
      for (int j = 0; j < c; ++j) {
        int other = __shfl(val, j);
        rank += (other < val) ? 1 : 0;
      }
      if (lane < c) {
        sorted[s + rank] = val;
        out_im[s + rank] = (float)val;
        out_at[val] = (float)(s + rank);
      }
    } else if (lane == 0) {
      for (int i = 1; i < c; ++i) {
        int key = sorted[s + i];
        int j = i - 1;
        while (j >= 0 && sorted[s + j] > key) {
          sorted[s + j + 1] = sorted[s + j];
          --j;
        }
        sorted[s + j + 1] = key;
      }
      for (int i = 0; i < c; ++i) {
        int aa = sorted[s + i];
        out_im[s + i] = (float)aa;
        out_at[aa] = (float)(s + i);
      }
    }
    int off = pairoff[b];
    int P = scalars[0];
    int np = c * (c - 1) / 2;
    for (int k = lane; k < np; k += 64) {
      int l = (int)((1.0f + sqrtf(1.0f + 8.0f * (float)k)) * 0.5f);
      while (l * (l - 1) / 2 > k) --l;
      while ((l + 1) * l / 2 <= k) ++l;
      int u = k - l * (l - 1) / 2;
      out[off + k] = (float)(s + u);
      out[P + off + k] = (float)(s + l);
    }
    return;
  }

  // emit: 16 lanes per atom, 16 atoms per block
  int a = (blockIdx.x - 2048) * 16 + (t >> 4);
  int l16 = t & 15;
  if (a >= n) return;
  int g0 = scalars[8], g1 = scalars[9], g2 = scalars[10], g12 = scalars[11];
  int p = pv[a];
  int v0 = p >> 20, v1 = (p >> 10) & 1023, v2 = p & 1023;
  int segs[8];
  int cums[7];
  segs[0] = 0;
#pragma unroll
  for (int m = 0; m < 7; ++m) {
    int dx = ((m >> 2) & 1) ? 0 : -1;
    int dy = ((m >> 1) & 1) ? 0 : -1;
    int dz = (m & 1) ? 0 : -1;
    int nx = v0 + dx; if (nx < 0) nx += g0;
    int ny = v1 + dy; if (ny < 0) ny += g1;
    int nz = v2 + dz; if (nz < 0) nz += g2;
    int nb_ = nx * g12 + ny * g1 + nz;
    cums[m] = cumc[nb_];
    segs[m + 1] = segs[m] + counts[nb_];
  }
  int S = segs[7];
  long base = 2L * (long)scalars[0] + (long)blockoff[a >> 8] + (long)Oarr[a];
  for (int q = l16; q < S; q += 16) {
    int v = cums[0] + q;
#pragma unroll
    for (int m = 1; m < 7; ++m) {
      if (q >= segs[m]) v = cums[m] + (q - segs[m]);
    }
    out[base + q] = (float)v;
  }
}

extern "C" void kernel_launch(void* const* d_in, const int* in_sizes, int n_in,
                              void* d_out, int out_size, void* d_ws, size_t ws_size,
                              hipStream_t stream) {
  const float* coord = (const float*)d_in[0];
  const float* cell = (const float*)d_in[1];
  float* out = (float*)d_out;
  int n = in_sizes[0] / 3;

  int* W = (int*)d_ws;
  int* counts = W;                         // NB_MAX
  int* fill = W + NB_MAX;                  // NB_MAX
  int* scalars = W + 2 * NB_MAX;           // 16 (zeroed)
  int* cumc = W + 2 * NB_MAX + 16;         // NB_MAX
  int* pairoff = cumc + NB_MAX;            // NB_MAX
  int* pv = pairoff + NB_MAX;              // n
  int* sorted = pv + n;                    // n
  int* Oarr = sorted + n;                  // n
  int* blockpart = Oarr + n;               // 1024
  int* blockoff = blockpart + 1024;        // 1024

  // output chunk bases known on host: out = [2P | L | 3n | n | n]
  float* out_frac = out + (out_size - 5 * n);
  float* out_im = out + (out_size - 2 * n);
  float* out_at = out + (out_size - n);

  int nblocks = (n + NTHR - 1) / NTHR;     // 391
  int eblocks = (n + 15) / 16;             // emit blocks (16 atoms each)

  hipMemsetAsync(d_ws, 0, (size_t)(2 * NB_MAX + 16) * sizeof(int), stream);

  k_count<<<nblocks, NTHR, 0, stream>>>(coord, cell, out_frac, pv, counts, scalars,
                                        cumc, pairoff, n);
  k_scatter<<<nblocks, NTHR, 0, stream>>>(pv, cumc, counts, scalars, fill, sorted,
                                          Oarr, blockpart, blockoff, n);
  k_sortemit<<<2048 + eblocks, NTHR, 0, stream>>>(counts, cumc, pairoff, scalars,
                                                  sorted, pv, Oarr, blockoff,
                                                  out_im, out_at, out, n);
}